// Round 12
// baseline (279.422 us; speedup 1.0000x reference)
//
#include <hip/hip_runtime.h>
#include <hip/hip_bf16.h>

// Problem constants
#define NN    16384      // N nodes
#define EE    262144     // edges
#define BNODES 32768     // B*N
#define AH    384        // A*H
#define TOT_NOISE 1572864u

typedef __attribute__((ext_vector_type(8))) short short8;
typedef __attribute__((ext_vector_type(4))) float v4f;

__device__ __forceinline__ unsigned short f2bf(float f) {
  unsigned u = __float_as_uint(f);
  unsigned r = u + 0x7fffu + ((u >> 16) & 1u);
  return (unsigned short)(r >> 16);
}
__device__ __forceinline__ float bf2f(unsigned short h) {
  return __uint_as_float(((unsigned)h) << 16);
}
__device__ __forceinline__ float bflo(unsigned u) { return __uint_as_float(u << 16); }
__device__ __forceinline__ float bfhi(unsigned u) { return __uint_as_float(u & 0xffff0000u); }
// HW packed fp32x2 -> bf16x2 (v_cvt_pk_bf16_f32, RNE — identical to f2bf)
__device__ __forceinline__ unsigned pk_bf16(float a, float b) {
  __hip_bfloat162 h = __float22bfloat162_rn(make_float2(a, b));
  return *(unsigned*)&h;
}

// ---------------------------------------------------------------------------
// Threefry-2x32, keys = (0, 42)
// ---------------------------------------------------------------------------
__device__ __forceinline__ void threefry2x32_042(unsigned& x0, unsigned& x1) {
  const unsigned ks0 = 0u;
  const unsigned ks1 = 42u;
  const unsigned ks2 = 0x1BD11BDAu ^ 0u ^ 42u;
  x0 += ks0; x1 += ks1;
#define TFR(r) { x0 += x1; x1 = (x1 << (r)) | (x1 >> (32 - (r))); x1 ^= x0; }
  TFR(13) TFR(15) TFR(26) TFR(6)   x0 += ks1; x1 += ks2 + 1u;
  TFR(17) TFR(29) TFR(16) TFR(24)  x0 += ks2; x1 += ks0 + 2u;
  TFR(13) TFR(15) TFR(26) TFR(6)   x0 += ks0; x1 += ks1 + 3u;
  TFR(17) TFR(29) TFR(16) TFR(24)  x0 += ks1; x1 += ks2 + 4u;
  TFR(13) TFR(15) TFR(26) TFR(6)   x0 += ks2; x1 += ks0 + 5u;
#undef TFR
}

// XLA ErfInv32 (Giles) polynomial
__device__ __forceinline__ float erfinv_f32(float x) {
  float w = -log1pf(-x * x);
  float p;
  if (w < 5.0f) {
    w -= 2.5f;
    p = 2.81022636e-08f;
    p = fmaf(p, w, 3.43273939e-07f);
    p = fmaf(p, w, -3.5233877e-06f);
    p = fmaf(p, w, -4.39150654e-06f);
    p = fmaf(p, w, 0.00021858087f);
    p = fmaf(p, w, -0.00125372503f);
    p = fmaf(p, w, -0.00417768164f);
    p = fmaf(p, w, 0.246640727f);
    p = fmaf(p, w, 1.50140941f);
  } else {
    w = sqrtf(w) - 3.0f;
    p = -0.000200214257f;
    p = fmaf(p, w, 0.000100950558f);
    p = fmaf(p, w, 0.00134934322f);
    p = fmaf(p, w, -0.00367342844f);
    p = fmaf(p, w, 0.00573950773f);
    p = fmaf(p, w, -0.0076224613f);
    p = fmaf(p, w, 0.00943887047f);
    p = fmaf(p, w, 1.00167406f);
    p = fmaf(p, w, 2.83297682f);
  }
  return p * x;
}

__device__ __forceinline__ unsigned jax_random_bits32(unsigned i) {
  unsigned x0 = 0u, x1 = i;
  threefry2x32_042(x0, x1);
  return x0 ^ x1;
}

__device__ __forceinline__ float jax_normal_from_bits(unsigned bits) {
  float f = __uint_as_float((bits >> 9) | 0x3f800000u) - 1.0f;  // [0,1)
  const float lo = -0.99999994f;                                 // nextafter(-1,0)
  float u = f * 2.0f + lo;
  u = fmaxf(u, lo);
  return 1.4142135623730951f * erfinv_f32(u);
}

// ---------------------------------------------------------------------------
// CSR build
// ---------------------------------------------------------------------------
__global__ void edge_count(const int* __restrict__ dst, int* __restrict__ deg) {
  int e = blockIdx.x * 256 + threadIdx.x;
  if (e < EE) atomicAdd(&deg[dst[e]], 1);
}

// scan_k also builds the 64-bin degree histogram prefix -> bincur (global),
// so the degree-sort scatter can run fully parallel (R11's single-block
// degsort was ~20 us of serial latency — Amdahl).
__global__ __launch_bounds__(1024) void scan_k(const int* __restrict__ deg,
                                               int* __restrict__ offs,
                                               int* __restrict__ cur,
                                               int* __restrict__ bincur) {
  __shared__ int wsum[16];
  __shared__ int hist[64];
  const int t = threadIdx.x;
  const int base = t * 16;
  if (t < 64) hist[t] = 0;
  int loc[16];
  int s = 0;
#pragma unroll
  for (int i = 0; i < 16; i++) { loc[i] = deg[base + i]; s += loc[i]; }
  __syncthreads();
#pragma unroll
  for (int i = 0; i < 16; i++) {
    int d = loc[i] > 63 ? 63 : loc[i];
    atomicAdd(&hist[d], 1);
  }
  const int mysum = s;
  const int lane = t & 63, wid = t >> 6;
#pragma unroll
  for (int off = 1; off < 64; off <<= 1) {
    int v = __shfl_up(s, off, 64);
    if (lane >= off) s += v;
  }
  if (lane == 63) wsum[wid] = s;
  __syncthreads();
  if (t == 0) {
    int r = 0;
#pragma unroll
    for (int i = 0; i < 16; i++) { int v = wsum[i]; wsum[i] = r; r += v; }
    int rb = 0;
    for (int i = 0; i < 64; i++) { int v = hist[i]; bincur[i] = rb; rb += v; }
  }
  __syncthreads();
  int run = wsum[wid] + s - mysum;
#pragma unroll
  for (int i = 0; i < 16; i++) {
    offs[base + i] = run;
    cur[base + i] = run;
    run += loc[i];
  }
  if (t == 1023) offs[NN] = run;
}

__global__ void edge_fill(const int* __restrict__ dst, const int* __restrict__ srcv,
                          int* __restrict__ cur, int* __restrict__ csr) {
  int e = blockIdx.x * 256 + threadIdx.x;
  if (e < EE) {
    int d = dst[e];
    int p = atomicAdd(&cur[d], 1);
    csr[p] = srcv[e];
  }
}

// Parallel counting-sort scatter: node -> perm slot in its degree bin.
// Order within a bin is nondeterministic — harmless (perm only picks
// node->block assignment; per-node arithmetic/order unchanged).
__global__ __launch_bounds__(256) void degscatter(const int* __restrict__ deg,
                                                  int* __restrict__ bincur,
                                                  int* __restrict__ perm) {
  int n = blockIdx.x * 256 + threadIdx.x;
  int d = deg[n]; if (d > 63) d = 63;
  int p = atomicAdd(&bincur[d], 1);
  perm[p] = n;
}

// ---------------------------------------------------------------------------
// Weight prep: slots 0-2: W1[a]; 3-5: W2[a]; 6-8: mu_W1[a]; 9:Wq 10:Wk 11:Wv
// 12:Wo  (each 16384)  |  slot 13 region: mu_W2 fragments (3 x 2048)
// ---------------------------------------------------------------------------
__global__ __launch_bounds__(256) void prep_wfrag(
    const float* __restrict__ W1, const float* __restrict__ W2,
    const float* __restrict__ mW1,
    const float* __restrict__ Wq, const float* __restrict__ Wk,
    const float* __restrict__ Wv, const float* __restrict__ Wo,
    const float* __restrict__ mW2,
    unsigned short* __restrict__ F) {
  int m = blockIdx.y;
  int f = blockIdx.x * 256 + threadIdx.x;
  if (m == 13) {   // mu_W2: A x 128 x 16
    if (f < 6144) {
      int a = f >> 11;
      int r2 = f & 2047;
      int kt = r2 >> 9;
      int r = r2 & 511;
      int lane = r >> 3, j = r & 7;
      int k = kt * 32 + (lane >> 4) * 8 + j;
      int n = lane & 15;
      F[13 * 16384 + f] = f2bf(mW2[(a * 128 + k) * 16 + n]);
    }
    return;
  }
  const float* W;
  if (m < 3) W = W1 + (long)m * 16384;
  else if (m < 6) W = W2 + (long)(m - 3) * 16384;
  else if (m < 9) W = mW1 + (long)(m - 6) * 16384;
  else W = (m == 9) ? Wq : (m == 10) ? Wk : (m == 11) ? Wv : Wo;
  int tile = f >> 9;
  int kt = tile >> 3, nt = tile & 7;
  int r = f & 511;
  int lane = r >> 3, j = r & 7;
  int k = kt * 32 + (lane >> 4) * 8 + j;
  int n = nt * 16 + (lane & 15);
  F[(long)m * 16384 + f] = f2bf(W[k * 128 + n]);
}

// ---------------------------------------------------------------------------
// Fused 2-layer MLP: h = relu(x@W1+b1)@W2 + b2, per a. 128-row tiles.
// ---------------------------------------------------------------------------
#define GXSTR 136
__global__ __launch_bounds__(256, 4) void mlp_fused(
    const float* __restrict__ X,
    const unsigned short* __restrict__ WF1, const float* __restrict__ b1,
    const unsigned short* __restrict__ WF2, const float* __restrict__ b2,
    unsigned short* __restrict__ H) {
  __shared__ __align__(16) unsigned short As[128 * GXSTR];
  const int a = blockIdx.y;
  const long m0 = (long)blockIdx.x * 128;
  const int tid = threadIdx.x;
  const unsigned short* Wp1 = WF1 + (long)a * 16384;
  const unsigned short* Wp2 = WF2 + (long)a * 16384;

  // stage x tile fp32 -> bf16 (HW packed convert)
#pragma unroll
  for (int p = 0; p < 8; p++) {
    int c = tid + p * 256;
    int row = c >> 4, c8 = (c & 15) * 8;
    float4 v1 = *(const float4*)(X + (m0 + row) * 128 + c8);
    float4 v2 = *(const float4*)(X + (m0 + row) * 128 + c8 + 4);
    uint4 o = make_uint4(pk_bf16(v1.x, v1.y), pk_bf16(v1.z, v1.w),
                         pk_bf16(v2.x, v2.y), pk_bf16(v2.z, v2.w));
    *(uint4*)(&As[row * GXSTR + c8]) = o;
  }
  __syncthreads();

  const int w = tid >> 6, l = tid & 63, lr = l & 15, lg = l >> 4;

  v4f acc[8][2];
#pragma unroll
  for (int mt = 0; mt < 8; mt++) {
    acc[mt][0] = (v4f){0.f, 0.f, 0.f, 0.f};
    acc[mt][1] = (v4f){0.f, 0.f, 0.f, 0.f};
  }
  // phase 1: t1 = x @ W1
#pragma unroll
  for (int kt = 0; kt < 4; kt++) {
    short8 bfr[2];
#pragma unroll
    for (int ntl = 0; ntl < 2; ntl++)
      bfr[ntl] = *(const short8*)(Wp1 + (long)(kt * 8 + 2 * w + ntl) * 512 + l * 8);
#pragma unroll
    for (int mt = 0; mt < 8; mt++) {
      short8 af = *(const short8*)(&As[(mt * 16 + lr) * GXSTR + kt * 32 + lg * 8]);
      acc[mt][0] = __builtin_amdgcn_mfma_f32_16x16x32_bf16(af, bfr[0], acc[mt][0], 0, 0, 0);
      acc[mt][1] = __builtin_amdgcn_mfma_f32_16x16x32_bf16(af, bfr[1], acc[mt][1], 0, 0, 0);
    }
  }
  __syncthreads();   // all As (x) reads done

  // write t1 = relu(acc + b1) back into As
  {
    float bv[2] = {b1[a * 128 + 32 * w + lr], b1[a * 128 + 32 * w + 16 + lr]};
#pragma unroll
    for (int mt = 0; mt < 8; mt++)
#pragma unroll
      for (int ntl = 0; ntl < 2; ntl++)
#pragma unroll
        for (int i = 0; i < 4; i++) {
          int row = mt * 16 + lg * 4 + i;
          int col = 32 * w + ntl * 16 + lr;
          As[row * GXSTR + col] = f2bf(fmaxf(acc[mt][ntl][i] + bv[ntl], 0.0f));
        }
  }
  __syncthreads();

  // phase 2: h = t1 @ W2 + b2
#pragma unroll
  for (int mt = 0; mt < 8; mt++) {
    acc[mt][0] = (v4f){0.f, 0.f, 0.f, 0.f};
    acc[mt][1] = (v4f){0.f, 0.f, 0.f, 0.f};
  }
#pragma unroll
  for (int kt = 0; kt < 4; kt++) {
    short8 bfr[2];
#pragma unroll
    for (int ntl = 0; ntl < 2; ntl++)
      bfr[ntl] = *(const short8*)(Wp2 + (long)(kt * 8 + 2 * w + ntl) * 512 + l * 8);
#pragma unroll
    for (int mt = 0; mt < 8; mt++) {
      short8 af = *(const short8*)(&As[(mt * 16 + lr) * GXSTR + kt * 32 + lg * 8]);
      acc[mt][0] = __builtin_amdgcn_mfma_f32_16x16x32_bf16(af, bfr[0], acc[mt][0], 0, 0, 0);
      acc[mt][1] = __builtin_amdgcn_mfma_f32_16x16x32_bf16(af, bfr[1], acc[mt][1], 0, 0, 0);
    }
  }
  {
    float bv[2] = {b2[a * 128 + 32 * w + lr], b2[a * 128 + 32 * w + 16 + lr]};
#pragma unroll
    for (int mt = 0; mt < 8; mt++)
#pragma unroll
      for (int ntl = 0; ntl < 2; ntl++)
#pragma unroll
        for (int i = 0; i < 4; i++) {
          long row = m0 + mt * 16 + lg * 4 + i;
          int col = 32 * w + ntl * 16 + lr;
          H[row * 384 + a * 128 + col] = f2bf(acc[mt][ntl][i] + bv[ntl]);
        }
  }
}

// ---------------------------------------------------------------------------
// Mega-fused: gather + attention + mu-MLP + noise/logp. 16 nodes/block,
// nodes taken via degree-sorted perm (balanced gather: wave max ~= mean).
// Gather: 16 threads/node, 48B/thread/edge, 2-edge register ping-pong.
// launch_bounds(256,3): VGPR cap ~170 keeps the ping-pong spill-free (R9).
// ---------------------------------------------------------------------------
#define XSTR 136
#define QSTR 34
__global__ __launch_bounds__(256, 3) void attn_mega(
    const unsigned short* __restrict__ H, const int* __restrict__ offs,
    const int* __restrict__ csr, const int* __restrict__ perm,
    const unsigned short* __restrict__ WF,
    const float* __restrict__ bq, const float* __restrict__ bk,
    const float* __restrict__ bv, const float* __restrict__ bo,
    const unsigned short* __restrict__ WM1, const float* __restrict__ mb1,
    const unsigned short* __restrict__ WM2, const float* __restrict__ mb2,
    float* __restrict__ out0, float* __restrict__ out1) {
  __shared__ __align__(16) unsigned short xS[48 * XSTR];
  __shared__ __align__(16) unsigned short kS[4 * 48 * QSTR];
  __shared__ __align__(16) unsigned short vS[4 * 48 * QSTR];
  __shared__ float lpS[48];
  __shared__ int ndS[16];

  const int tid = threadIdx.x;
  const int bt = blockIdx.x >> 10;            // batch (1024 groups per batch)
  const int grp = blockIdx.x & 1023;

  // ---- phase 0: gather + segment-sum agg for 16 nodes directly into xS ----
  {
    const int nd = tid >> 4;                     // 0..15 local node
    const int sub = tid & 15;                    // 0..15 col group (24 bf16)
    const int n = perm[grp * 16 + nd];
    if (sub == 0) ndS[nd] = n;
    const int e0 = offs[n], e1 = offs[n + 1];
    const unsigned short* hb = H + (long)bt * NN * 384 + sub * 24;
    float acc24[24];
#pragma unroll
    for (int i = 0; i < 24; i++) acc24[i] = 0.f;

#define ACC8(base, u)                                                   \
    { acc24[base+0] += bflo(u.x); acc24[base+1] += bfhi(u.x);           \
      acc24[base+2] += bflo(u.y); acc24[base+3] += bfhi(u.y);           \
      acc24[base+4] += bflo(u.z); acc24[base+5] += bfhi(u.z);           \
      acc24[base+6] += bflo(u.w); acc24[base+7] += bfhi(u.w); }
#define LDPAIR(B0,B1,B2,B3,B4,B5, jj)                                   \
    { int s0 = csr[jj], s1 = csr[(jj) + 1];                             \
      const unsigned short* p0 = hb + (long)s0 * 384;                   \
      const unsigned short* p1 = hb + (long)s1 * 384;                   \
      B0 = *(const uint4*)(p0);  B1 = *(const uint4*)(p0 + 8);          \
      B2 = *(const uint4*)(p0 + 16);                                    \
      B3 = *(const uint4*)(p1);  B4 = *(const uint4*)(p1 + 8);          \
      B5 = *(const uint4*)(p1 + 16); }
#define ACCP(B0,B1,B2,B3,B4,B5)                                         \
    { ACC8(0,B0) ACC8(8,B1) ACC8(16,B2) ACC8(0,B3) ACC8(8,B4) ACC8(16,B5) }

    const int npair = (e1 - e0) >> 1;
    int j = e0;
    if (npair > 0) {
      uint4 a0, a1, a2, a3, a4, a5;
      uint4 b0, b1, b2, b3, b4, b5;
      LDPAIR(a0, a1, a2, a3, a4, a5, j);
      int g = 0;
      while (true) {
        if (g + 1 < npair) {
          LDPAIR(b0, b1, b2, b3, b4, b5, j + 2);   // in flight while acc A
          ACCP(a0, a1, a2, a3, a4, a5);
          g++; j += 2;
          if (g + 1 < npair) {
            LDPAIR(a0, a1, a2, a3, a4, a5, j + 2); // in flight while acc B
            ACCP(b0, b1, b2, b3, b4, b5);
            g++; j += 2;
          } else {
            ACCP(b0, b1, b2, b3, b4, b5);
            g++; j += 2;
            break;
          }
        } else {
          ACCP(a0, a1, a2, a3, a4, a5);
          g++; j += 2;
          break;
        }
      }
    }
    if (j < e1) {   // at most one leftover edge
      int s0 = csr[j];
      const unsigned short* p0 = hb + (long)s0 * 384;
      uint4 A0 = *(const uint4*)(p0);
      uint4 A1 = *(const uint4*)(p0 + 8);
      uint4 A2 = *(const uint4*)(p0 + 16);
      ACC8(0, A0) ACC8(8, A1) ACC8(16, A2)
    }
#undef ACCP
#undef LDPAIR
#undef ACC8
    // write agg -> xS rows (3*nd + a), packed pairs (pairs never cross a)
#pragma unroll
    for (int jj = 0; jj < 12; jj++) {
      int g = sub * 24 + 2 * jj;
      int a_ = g >> 7;
      int c = g & 127;
      *(unsigned*)&xS[(3 * nd + a_) * XSTR + c] =
          pk_bf16(acc24[2 * jj], acc24[2 * jj + 1]);
    }
  }
  __syncthreads();

  const int w = tid >> 6;
  const int l = tid & 63;
  const int lr = l & 15;
  const int lg = l >> 4;
  const unsigned short* WQ = WF;
  const unsigned short* WK = WF + 16384;
  const unsigned short* WV = WF + 32768;
  const unsigned short* WO = WF + 49152;

  // ---- phase 1: QKV projections ----
  v4f accq[3][2], acck[3][2], accv[3][2];
#pragma unroll
  for (int mt = 0; mt < 3; mt++)
#pragma unroll
    for (int n = 0; n < 2; n++) {
      accq[mt][n] = (v4f){0.f, 0.f, 0.f, 0.f};
      acck[mt][n] = (v4f){0.f, 0.f, 0.f, 0.f};
      accv[mt][n] = (v4f){0.f, 0.f, 0.f, 0.f};
    }
#pragma unroll
  for (int kt = 0; kt < 4; kt++) {
    short8 af[3];
#pragma unroll
    for (int mt = 0; mt < 3; mt++)
      af[mt] = *(const short8*)&xS[(mt * 16 + lr) * XSTR + kt * 32 + lg * 8];
#pragma unroll
    for (int ntl = 0; ntl < 2; ntl++) {
      long tf = (long)(kt * 8 + 2 * w + ntl) * 512 + l * 8;
      short8 b0 = *(const short8*)&WQ[tf];
      short8 b1 = *(const short8*)&WK[tf];
      short8 b2 = *(const short8*)&WV[tf];
#pragma unroll
      for (int mt = 0; mt < 3; mt++) {
        accq[mt][ntl] = __builtin_amdgcn_mfma_f32_16x16x32_bf16(af[mt], b0, accq[mt][ntl], 0, 0, 0);
        acck[mt][ntl] = __builtin_amdgcn_mfma_f32_16x16x32_bf16(af[mt], b1, acck[mt][ntl], 0, 0, 0);
        accv[mt][ntl] = __builtin_amdgcn_mfma_f32_16x16x32_bf16(af[mt], b2, accv[mt][ntl], 0, 0, 0);
      }
    }
  }
  __syncthreads();   // all waves' xS (agg) MFMA reads complete

  // residual pre-read (per-wave own head cols of xS), THEN write Q over them
  float resv[3][2][4];
#pragma unroll
  for (int mt = 0; mt < 3; mt++)
#pragma unroll
    for (int ntl = 0; ntl < 2; ntl++)
#pragma unroll
      for (int i = 0; i < 4; i++)
        resv[mt][ntl][i] =
            bf2f(xS[(mt * 16 + lg * 4 + i) * XSTR + 32 * w + ntl * 16 + lr]);

  {
    const float scale = 0.17677669529663687f;  // 1/sqrt(32)
    unsigned short* kw = &kS[w * 48 * QSTR];
    unsigned short* vw = &vS[w * 48 * QSTR];
    float bqv[2] = {bq[32 * w + lr], bq[32 * w + 16 + lr]};
    float bkv[2] = {bk[32 * w + lr], bk[32 * w + 16 + lr]};
    float bvv[2] = {bv[32 * w + lr], bv[32 * w + 16 + lr]};
#pragma unroll
    for (int mt = 0; mt < 3; mt++)
#pragma unroll
      for (int ntl = 0; ntl < 2; ntl++)
#pragma unroll
        for (int i = 0; i < 4; i++) {
          int row = mt * 16 + lg * 4 + i;
          int col = ntl * 16 + lr;
          xS[row * XSTR + 32 * w + col] = f2bf((accq[mt][ntl][i] + bqv[ntl]) * scale);
          kw[row * QSTR + col] = f2bf(acck[mt][ntl][i] + bkv[ntl]);
          vw[row * QSTR + col] = f2bf(accv[mt][ntl][i] + bvv[ntl]);
        }
  }
  __syncthreads();

  // ---- phase 2: attention; lane l<48 owns (nd=l/3, aq=l%3) of head w.
  // O overwrites lane's own Q row in xS — race-free.
  if (l < 48) {
    int aq = l % 3;
    int ndr = l - aq;
    const unsigned* qr = (const unsigned*)&xS[l * XSTR + 32 * w];
    const unsigned* kr0 = (const unsigned*)&kS[(w * 48 + ndr) * QSTR];
    const unsigned* kr1 = (const unsigned*)&kS[(w * 48 + ndr + 1) * QSTR];
    const unsigned* kr2 = (const unsigned*)&kS[(w * 48 + ndr + 2) * QSTR];
    float s0 = 0.f, s1 = 0.f, s2 = 0.f;
#pragma unroll
    for (int j = 0; j < 16; j++) {
      unsigned uq = qr[j], u0 = kr0[j], u1 = kr1[j], u2 = kr2[j];
      float qa = bflo(uq), qb = bfhi(uq);
      s0 = fmaf(qa, bflo(u0), fmaf(qb, bfhi(u0), s0));
      s1 = fmaf(qa, bflo(u1), fmaf(qb, bfhi(u1), s1));
      s2 = fmaf(qa, bflo(u2), fmaf(qb, bfhi(u2), s2));
    }
    float mx = fmaxf(s0, fmaxf(s1, s2));
    float e0 = expf(s0 - mx), e1 = expf(s1 - mx), e2 = expf(s2 - mx);
    float inv = 1.0f / (e0 + e1 + e2);
    e0 *= inv; e1 *= inv; e2 *= inv;
    const unsigned* vr0 = (const unsigned*)&vS[(w * 48 + ndr) * QSTR];
    const unsigned* vr1 = (const unsigned*)&vS[(w * 48 + ndr + 1) * QSTR];
    const unsigned* vr2 = (const unsigned*)&vS[(w * 48 + ndr + 2) * QSTR];
    unsigned ov[16];
#pragma unroll
    for (int j = 0; j < 16; j++) {
      unsigned u0 = vr0[j], u1 = vr1[j], u2 = vr2[j];
      float oa = fmaf(e0, bflo(u0), fmaf(e1, bflo(u1), e2 * bflo(u2)));
      float ob = fmaf(e0, bfhi(u0), fmaf(e1, bfhi(u1), e2 * bfhi(u2)));
      ov[j] = pk_bf16(oa, ob);
    }
    uint4* orow = (uint4*)&xS[l * XSTR + 32 * w];
    orow[0] = make_uint4(ov[0], ov[1], ov[2], ov[3]);
    orow[1] = make_uint4(ov[4], ov[5], ov[6], ov[7]);
    orow[2] = make_uint4(ov[8], ov[9], ov[10], ov[11]);
    orow[3] = make_uint4(ov[12], ov[13], ov[14], ov[15]);
  }
  __syncthreads();

  // ---- phase 3: hI = agg + O @ Wo + bo ----
  v4f acco[3][2];
#pragma unroll
  for (int mt = 0; mt < 3; mt++)
#pragma unroll
    for (int n = 0; n < 2; n++) acco[mt][n] = (v4f){0.f, 0.f, 0.f, 0.f};
#pragma unroll
  for (int kt = 0; kt < 4; kt++) {
    short8 af[3];
#pragma unroll
    for (int mt = 0; mt < 3; mt++)
      af[mt] = *(const short8*)&xS[(mt * 16 + lr) * XSTR + kt * 32 + lg * 8];
#pragma unroll
    for (int ntl = 0; ntl < 2; ntl++) {
      long tf = (long)(kt * 8 + 2 * w + ntl) * 512 + l * 8;
      short8 b = *(const short8*)&WO[tf];
#pragma unroll
      for (int mt = 0; mt < 3; mt++)
        acco[mt][ntl] = __builtin_amdgcn_mfma_f32_16x16x32_bf16(af[mt], b, acco[mt][ntl], 0, 0, 0);
    }
  }
  __syncthreads();   // all O reads of xS done

  // write hI into xS, a-major rows: row' = a*16 + nd  (orig row = 3*nd + a)
  {
    float bov[2] = {bo[32 * w + lr], bo[32 * w + 16 + lr]};
#pragma unroll
    for (int mt = 0; mt < 3; mt++)
#pragma unroll
      for (int ntl = 0; ntl < 2; ntl++)
#pragma unroll
        for (int i = 0; i < 4; i++) {
          int row = mt * 16 + lg * 4 + i;
          int nd = row / 3, a_ = row - nd * 3;
          int gcol = 32 * w + ntl * 16 + lr;
          xS[(a_ * 16 + nd) * XSTR + gcol] =
              f2bf(acco[mt][ntl][i] + bov[ntl] + resv[mt][ntl][i]);
        }
  }
  __syncthreads();

  // ---- phase 4: m = relu(hI @ mu_W1[a] + mb1[a]); tile mt == a ----
  v4f accm[3][2];
#pragma unroll
  for (int mt = 0; mt < 3; mt++)
#pragma unroll
    for (int n = 0; n < 2; n++) accm[mt][n] = (v4f){0.f, 0.f, 0.f, 0.f};
#pragma unroll
  for (int kt = 0; kt < 4; kt++) {
#pragma unroll
    for (int mt = 0; mt < 3; mt++) {
      short8 af = *(const short8*)&xS[(mt * 16 + lr) * XSTR + kt * 32 + lg * 8];
#pragma unroll
      for (int ntl = 0; ntl < 2; ntl++) {
        short8 b = *(const short8*)(WM1 + (long)mt * 16384 +
                                    (long)(kt * 8 + 2 * w + ntl) * 512 + l * 8);
        accm[mt][ntl] = __builtin_amdgcn_mfma_f32_16x16x32_bf16(af, b, accm[mt][ntl], 0, 0, 0);
      }
    }
  }
  __syncthreads();   // all hI reads done

  // write m into xS (already a-major: tile mt rows = a*16 + nd)
#pragma unroll
  for (int mt = 0; mt < 3; mt++)
#pragma unroll
    for (int ntl = 0; ntl < 2; ntl++) {
      int col = 32 * w + ntl * 16 + lr;
      float bias = mb1[mt * 128 + col];
#pragma unroll
      for (int i = 0; i < 4; i++) {
        int rowp = mt * 16 + lg * 4 + i;
        xS[rowp * XSTR + col] = f2bf(fmaxf(accm[mt][ntl][i] + bias, 0.0f));
      }
    }
  __syncthreads();

  // ---- phase 5: mu = m @ mu_W2[a] + mb2[a]; wave w handles a = w (w<3) ----
  if (w < 3) {
    v4f accu = (v4f){0.f, 0.f, 0.f, 0.f};
#pragma unroll
    for (int kt = 0; kt < 4; kt++) {
      short8 af = *(const short8*)&xS[(w * 16 + lr) * XSTR + kt * 32 + lg * 8];
      short8 b = *(const short8*)(WM2 + w * 2048 + kt * 512 + l * 8);
      accu = __builtin_amdgcn_mfma_f32_16x16x32_bf16(af, b, accu, 0, 0, 0);
    }
    float bias = mb2[w * 16 + lr];
#pragma unroll
    for (int i = 0; i < 4; i++) {
      int nd = lg * 4 + i;
      int node = ndS[nd];
      float mu = accu[i] + bias;
      unsigned gidx = (unsigned)(((long)bt * NN + node) * 48 + w * 16 + lr);
      unsigned bits = jax_random_bits32(gidx);
      float noise = jax_normal_from_bits(bits);
      float sample = mu + noise;
      float lp = -0.9189385332046727f - 0.5f * noise * noise;
      lp += __shfl_xor(lp, 1, 64);
      lp += __shfl_xor(lp, 2, 64);
      lp += __shfl_xor(lp, 4, 64);
      lp += __shfl_xor(lp, 8, 64);
      if (lr == 0) lpS[w * 16 + nd] = lp;
      float res;
      if (w == 0) {
        float th = tanhf(sample);
        float mx = th;
        mx = fmaxf(mx, __shfl_xor(mx, 1, 64));
        mx = fmaxf(mx, __shfl_xor(mx, 2, 64));
        mx = fmaxf(mx, __shfl_xor(mx, 4, 64));
        mx = fmaxf(mx, __shfl_xor(mx, 8, 64));
        float ex = expf(th - mx);
        float ss = ex;
        ss += __shfl_xor(ss, 1, 64);
        ss += __shfl_xor(ss, 2, 64);
        ss += __shfl_xor(ss, 4, 64);
        ss += __shfl_xor(ss, 8, 64);
        res = ex / ss;
      } else if (w == 1) {
        res = 1.0f / (1.0f + expf(-sample));
      } else {
        res = tanhf(sample);
      }
      out0[gidx] = res;
    }
  }
  __syncthreads();
  if (tid < 16)
    out1[(long)bt * NN + ndS[tid]] = lpS[tid] + lpS[16 + tid] + lpS[32 + tid];
}

// ---------------------------------------------------------------------------
extern "C" void kernel_launch(void* const* d_in, const int* in_sizes, int n_in,
                              void* d_out, int out_size, void* d_ws, size_t ws_size,
                              hipStream_t stream) {
  const float* x = (const float*)d_in[0];
  const int* ei = (const int*)d_in[1];
  const float* W1 = (const float*)d_in[2];
  const float* b1 = (const float*)d_in[3];
  const float* W2 = (const float*)d_in[4];
  const float* b2 = (const float*)d_in[5];
  const float* Wq = (const float*)d_in[6];
  const float* bq = (const float*)d_in[7];
  const float* Wk = (const float*)d_in[8];
  const float* bk = (const float*)d_in[9];
  const float* Wv = (const float*)d_in[10];
  const float* bv = (const float*)d_in[11];
  const float* Wo = (const float*)d_in[12];
  const float* bo = (const float*)d_in[13];
  const float* mW1 = (const float*)d_in[14];
  const float* mb1 = (const float*)d_in[15];
  const float* mW2 = (const float*)d_in[16];
  const float* mb2 = (const float*)d_in[17];
  (void)in_sizes; (void)n_in; (void)out_size; (void)ws_size;

  unsigned short* HB = (unsigned short*)d_ws;      // 12,582,912 (h bf16)
  int* deg = (int*)(HB + 12582912);                // 16384
  int* offs = deg + NN;                            // 16385
  int* cur = offs + (NN + 1);                      // 16384
  int* csr = cur + NN;                             // 262144
  int* perm = csr + EE;                            // 16384
  int* bincur = perm + NN;                         // 64
  unsigned short* wfrag = (unsigned short*)(((uintptr_t)(bincur + 64) + 15) & ~(uintptr_t)15);
  unsigned short* w2frag = wfrag + 13 * 16384;     // 3*2048

  const int* dst = ei;
  const int* srcv = ei + EE;

  float* out0 = (float*)d_out;
  float* out1 = out0 + TOT_NOISE;

  hipMemsetAsync(deg, 0, NN * sizeof(int), stream);
  edge_count<<<EE / 256, 256, 0, stream>>>(dst, deg);
  scan_k<<<1, 1024, 0, stream>>>(deg, offs, cur, bincur);
  edge_fill<<<EE / 256, 256, 0, stream>>>(dst, srcv, cur, csr);
  degscatter<<<NN / 256, 256, 0, stream>>>(deg, bincur, perm);
  prep_wfrag<<<dim3(64, 14), 256, 0, stream>>>(W1, W2, mW1, Wq, Wk, Wv, Wo, mW2, wfrag);

  // h = relu(x@W1+b1)@W2 + b2  (fused 2-layer MLP)
  mlp_fused<<<dim3(BNODES / 128, 3), 256, 0, stream>>>(x, wfrag, b1, wfrag + 3 * 16384, b2, HB);
  // gather + attention + hI + mu-MLP + noise/logp (mega-fused, degree-sorted)
  attn_mega<<<BNODES / 16, 256, 0, stream>>>(HB, offs, csr, perm,
                                             wfrag + 9 * 16384, bq, bk, bv, bo,
                                             wfrag + 6 * 16384, mb1, w2frag, mb2,
                                             out0, out1);
}

// Round 13
// 234.064 us; speedup vs baseline: 1.1938x; 1.1938x over previous
//
#include <hip/hip_runtime.h>
#include <hip/hip_bf16.h>

// Problem constants
#define NN    16384      // N nodes
#define EE    262144     // edges
#define BNODES 32768     // B*N
#define AH    384        // A*H
#define TOT_NOISE 1572864u

typedef __attribute__((ext_vector_type(8))) short short8;
typedef __attribute__((ext_vector_type(4))) float v4f;

__device__ __forceinline__ unsigned short f2bf(float f) {
  unsigned u = __float_as_uint(f);
  unsigned r = u + 0x7fffu + ((u >> 16) & 1u);
  return (unsigned short)(r >> 16);
}
__device__ __forceinline__ float bf2f(unsigned short h) {
  return __uint_as_float(((unsigned)h) << 16);
}
__device__ __forceinline__ float bflo(unsigned u) { return __uint_as_float(u << 16); }
__device__ __forceinline__ float bfhi(unsigned u) { return __uint_as_float(u & 0xffff0000u); }
// HW packed fp32x2 -> bf16x2 (v_cvt_pk_bf16_f32, RNE — identical to f2bf)
__device__ __forceinline__ unsigned pk_bf16(float a, float b) {
  __hip_bfloat162 h = __float22bfloat162_rn(make_float2(a, b));
  return *(unsigned*)&h;
}

// ---------------------------------------------------------------------------
// Threefry-2x32, keys = (0, 42)
// ---------------------------------------------------------------------------
__device__ __forceinline__ void threefry2x32_042(unsigned& x0, unsigned& x1) {
  const unsigned ks0 = 0u;
  const unsigned ks1 = 42u;
  const unsigned ks2 = 0x1BD11BDAu ^ 0u ^ 42u;
  x0 += ks0; x1 += ks1;
#define TFR(r) { x0 += x1; x1 = (x1 << (r)) | (x1 >> (32 - (r))); x1 ^= x0; }
  TFR(13) TFR(15) TFR(26) TFR(6)   x0 += ks1; x1 += ks2 + 1u;
  TFR(17) TFR(29) TFR(16) TFR(24)  x0 += ks2; x1 += ks0 + 2u;
  TFR(13) TFR(15) TFR(26) TFR(6)   x0 += ks0; x1 += ks1 + 3u;
  TFR(17) TFR(29) TFR(16) TFR(24)  x0 += ks1; x1 += ks2 + 4u;
  TFR(13) TFR(15) TFR(26) TFR(6)   x0 += ks2; x1 += ks0 + 5u;
#undef TFR
}

// XLA ErfInv32 (Giles) polynomial
__device__ __forceinline__ float erfinv_f32(float x) {
  float w = -log1pf(-x * x);
  float p;
  if (w < 5.0f) {
    w -= 2.5f;
    p = 2.81022636e-08f;
    p = fmaf(p, w, 3.43273939e-07f);
    p = fmaf(p, w, -3.5233877e-06f);
    p = fmaf(p, w, -4.39150654e-06f);
    p = fmaf(p, w, 0.00021858087f);
    p = fmaf(p, w, -0.00125372503f);
    p = fmaf(p, w, -0.00417768164f);
    p = fmaf(p, w, 0.246640727f);
    p = fmaf(p, w, 1.50140941f);
  } else {
    w = sqrtf(w) - 3.0f;
    p = -0.000200214257f;
    p = fmaf(p, w, 0.000100950558f);
    p = fmaf(p, w, 0.00134934322f);
    p = fmaf(p, w, -0.00367342844f);
    p = fmaf(p, w, 0.00573950773f);
    p = fmaf(p, w, -0.0076224613f);
    p = fmaf(p, w, 0.00943887047f);
    p = fmaf(p, w, 1.00167406f);
    p = fmaf(p, w, 2.83297682f);
  }
  return p * x;
}

__device__ __forceinline__ unsigned jax_random_bits32(unsigned i) {
  unsigned x0 = 0u, x1 = i;
  threefry2x32_042(x0, x1);
  return x0 ^ x1;
}

__device__ __forceinline__ float jax_normal_from_bits(unsigned bits) {
  float f = __uint_as_float((bits >> 9) | 0x3f800000u) - 1.0f;  // [0,1)
  const float lo = -0.99999994f;                                 // nextafter(-1,0)
  float u = f * 2.0f + lo;
  u = fmaxf(u, lo);
  return 1.4142135623730951f * erfinv_f32(u);
}

// ---------------------------------------------------------------------------
// CSR build
// ---------------------------------------------------------------------------
__global__ void edge_count(const int* __restrict__ dst, int* __restrict__ deg) {
  int e = blockIdx.x * 256 + threadIdx.x;
  if (e < EE) atomicAdd(&deg[dst[e]], 1);
}

__global__ __launch_bounds__(1024) void scan_k(const int* __restrict__ deg,
                                               int* __restrict__ offs,
                                               int* __restrict__ cur) {
  __shared__ int wsum[16];
  const int t = threadIdx.x;
  const int base = t * 16;
  int loc[16];
  int s = 0;
#pragma unroll
  for (int i = 0; i < 16; i++) { loc[i] = deg[base + i]; s += loc[i]; }
  const int mysum = s;
  const int lane = t & 63, wid = t >> 6;
#pragma unroll
  for (int off = 1; off < 64; off <<= 1) {
    int v = __shfl_up(s, off, 64);
    if (lane >= off) s += v;
  }
  if (lane == 63) wsum[wid] = s;
  __syncthreads();
  if (t == 0) {
    int r = 0;
#pragma unroll
    for (int i = 0; i < 16; i++) { int v = wsum[i]; wsum[i] = r; r += v; }
  }
  __syncthreads();
  int run = wsum[wid] + s - mysum;
#pragma unroll
  for (int i = 0; i < 16; i++) {
    offs[base + i] = run;
    cur[base + i] = run;
    run += loc[i];
  }
  if (t == 1023) offs[NN] = run;
}

__global__ void edge_fill(const int* __restrict__ dst, const int* __restrict__ srcv,
                          int* __restrict__ cur, int* __restrict__ csr) {
  int e = blockIdx.x * 256 + threadIdx.x;
  if (e < EE) {
    int d = dst[e];
    int p = atomicAdd(&cur[d], 1);
    csr[p] = srcv[e];
  }
}

// ---------------------------------------------------------------------------
// Weight prep: slots 0-2: W1[a]; 3-5: W2[a]; 6-8: mu_W1[a]; 9:Wq 10:Wk 11:Wv
// 12:Wo  (each 16384)  |  slot 13 region: mu_W2 fragments (3 x 2048)
// ---------------------------------------------------------------------------
__global__ __launch_bounds__(256) void prep_wfrag(
    const float* __restrict__ W1, const float* __restrict__ W2,
    const float* __restrict__ mW1,
    const float* __restrict__ Wq, const float* __restrict__ Wk,
    const float* __restrict__ Wv, const float* __restrict__ Wo,
    const float* __restrict__ mW2,
    unsigned short* __restrict__ F) {
  int m = blockIdx.y;
  int f = blockIdx.x * 256 + threadIdx.x;
  if (m == 13) {   // mu_W2: A x 128 x 16
    if (f < 6144) {
      int a = f >> 11;
      int r2 = f & 2047;
      int kt = r2 >> 9;
      int r = r2 & 511;
      int lane = r >> 3, j = r & 7;
      int k = kt * 32 + (lane >> 4) * 8 + j;
      int n = lane & 15;
      F[13 * 16384 + f] = f2bf(mW2[(a * 128 + k) * 16 + n]);
    }
    return;
  }
  const float* W;
  if (m < 3) W = W1 + (long)m * 16384;
  else if (m < 6) W = W2 + (long)(m - 3) * 16384;
  else if (m < 9) W = mW1 + (long)(m - 6) * 16384;
  else W = (m == 9) ? Wq : (m == 10) ? Wk : (m == 11) ? Wv : Wo;
  int tile = f >> 9;
  int kt = tile >> 3, nt = tile & 7;
  int r = f & 511;
  int lane = r >> 3, j = r & 7;
  int k = kt * 32 + (lane >> 4) * 8 + j;
  int n = nt * 16 + (lane & 15);
  F[(long)m * 16384 + f] = f2bf(W[k * 128 + n]);
}

// ---------------------------------------------------------------------------
// Fused 2-layer MLP: h = relu(x@W1+b1)@W2 + b2, per a. 128-row tiles.
// ---------------------------------------------------------------------------
#define GXSTR 136
__global__ __launch_bounds__(256, 4) void mlp_fused(
    const float* __restrict__ X,
    const unsigned short* __restrict__ WF1, const float* __restrict__ b1,
    const unsigned short* __restrict__ WF2, const float* __restrict__ b2,
    unsigned short* __restrict__ H) {
  __shared__ __align__(16) unsigned short As[128 * GXSTR];
  const int a = blockIdx.y;
  const long m0 = (long)blockIdx.x * 128;
  const int tid = threadIdx.x;
  const unsigned short* Wp1 = WF1 + (long)a * 16384;
  const unsigned short* Wp2 = WF2 + (long)a * 16384;

  // stage x tile fp32 -> bf16 (HW packed convert)
#pragma unroll
  for (int p = 0; p < 8; p++) {
    int c = tid + p * 256;
    int row = c >> 4, c8 = (c & 15) * 8;
    float4 v1 = *(const float4*)(X + (m0 + row) * 128 + c8);
    float4 v2 = *(const float4*)(X + (m0 + row) * 128 + c8 + 4);
    uint4 o = make_uint4(pk_bf16(v1.x, v1.y), pk_bf16(v1.z, v1.w),
                         pk_bf16(v2.x, v2.y), pk_bf16(v2.z, v2.w));
    *(uint4*)(&As[row * GXSTR + c8]) = o;
  }
  __syncthreads();

  const int w = tid >> 6, l = tid & 63, lr = l & 15, lg = l >> 4;

  v4f acc[8][2];
#pragma unroll
  for (int mt = 0; mt < 8; mt++) {
    acc[mt][0] = (v4f){0.f, 0.f, 0.f, 0.f};
    acc[mt][1] = (v4f){0.f, 0.f, 0.f, 0.f};
  }
  // phase 1: t1 = x @ W1
#pragma unroll
  for (int kt = 0; kt < 4; kt++) {
    short8 bfr[2];
#pragma unroll
    for (int ntl = 0; ntl < 2; ntl++)
      bfr[ntl] = *(const short8*)(Wp1 + (long)(kt * 8 + 2 * w + ntl) * 512 + l * 8);
#pragma unroll
    for (int mt = 0; mt < 8; mt++) {
      short8 af = *(const short8*)(&As[(mt * 16 + lr) * GXSTR + kt * 32 + lg * 8]);
      acc[mt][0] = __builtin_amdgcn_mfma_f32_16x16x32_bf16(af, bfr[0], acc[mt][0], 0, 0, 0);
      acc[mt][1] = __builtin_amdgcn_mfma_f32_16x16x32_bf16(af, bfr[1], acc[mt][1], 0, 0, 0);
    }
  }
  __syncthreads();   // all As (x) reads done

  // write t1 = relu(acc + b1) back into As
  {
    float bv[2] = {b1[a * 128 + 32 * w + lr], b1[a * 128 + 32 * w + 16 + lr]};
#pragma unroll
    for (int mt = 0; mt < 8; mt++)
#pragma unroll
      for (int ntl = 0; ntl < 2; ntl++)
#pragma unroll
        for (int i = 0; i < 4; i++) {
          int row = mt * 16 + lg * 4 + i;
          int col = 32 * w + ntl * 16 + lr;
          As[row * GXSTR + col] = f2bf(fmaxf(acc[mt][ntl][i] + bv[ntl], 0.0f));
        }
  }
  __syncthreads();

  // phase 2: h = t1 @ W2 + b2
#pragma unroll
  for (int mt = 0; mt < 8; mt++) {
    acc[mt][0] = (v4f){0.f, 0.f, 0.f, 0.f};
    acc[mt][1] = (v4f){0.f, 0.f, 0.f, 0.f};
  }
#pragma unroll
  for (int kt = 0; kt < 4; kt++) {
    short8 bfr[2];
#pragma unroll
    for (int ntl = 0; ntl < 2; ntl++)
      bfr[ntl] = *(const short8*)(Wp2 + (long)(kt * 8 + 2 * w + ntl) * 512 + l * 8);
#pragma unroll
    for (int mt = 0; mt < 8; mt++) {
      short8 af = *(const short8*)(&As[(mt * 16 + lr) * GXSTR + kt * 32 + lg * 8]);
      acc[mt][0] = __builtin_amdgcn_mfma_f32_16x16x32_bf16(af, bfr[0], acc[mt][0], 0, 0, 0);
      acc[mt][1] = __builtin_amdgcn_mfma_f32_16x16x32_bf16(af, bfr[1], acc[mt][1], 0, 0, 0);
    }
  }
  {
    float bv[2] = {b2[a * 128 + 32 * w + lr], b2[a * 128 + 32 * w + 16 + lr]};
#pragma unroll
    for (int mt = 0; mt < 8; mt++)
#pragma unroll
      for (int ntl = 0; ntl < 2; ntl++)
#pragma unroll
        for (int i = 0; i < 4; i++) {
          long row = m0 + mt * 16 + lg * 4 + i;
          int col = 32 * w + ntl * 16 + lr;
          H[row * 384 + a * 128 + col] = f2bf(acc[mt][ntl][i] + bv[ntl]);
        }
  }
}

// ---------------------------------------------------------------------------
// Mega-fused: gather + attention + mu-MLP + noise/logp. 16 nodes/block.
// Gather: 16 threads/node, 48B/thread/edge, 2-edge register ping-pong.
// launch_bounds(256,3): VGPR cap ~170 keeps the ping-pong spill-free (R9).
// ---------------------------------------------------------------------------
#define XSTR 136
#define QSTR 34
__global__ __launch_bounds__(256, 3) void attn_mega(
    const unsigned short* __restrict__ H, const int* __restrict__ offs,
    const int* __restrict__ csr,
    const unsigned short* __restrict__ WF,
    const float* __restrict__ bq, const float* __restrict__ bk,
    const float* __restrict__ bv, const float* __restrict__ bo,
    const unsigned short* __restrict__ WM1, const float* __restrict__ mb1,
    const unsigned short* __restrict__ WM2, const float* __restrict__ mb2,
    float* __restrict__ out0, float* __restrict__ out1) {
  __shared__ __align__(16) unsigned short xS[48 * XSTR];
  __shared__ __align__(16) unsigned short kS[4 * 48 * QSTR];
  __shared__ __align__(16) unsigned short vS[4 * 48 * QSTR];
  __shared__ float lpS[48];

  const int tid = threadIdx.x;
  const long node0 = (long)blockIdx.x * 16;

  // ---- phase 0: gather + segment-sum agg for 16 nodes directly into xS ----
  {
    const int bt = (int)(node0 >> 14);           // batch
    const int nbase = (int)(node0 & (NN - 1));
    const int nd = tid >> 4;                     // 0..15 local node
    const int sub = tid & 15;                    // 0..15 col group (24 bf16)
    const int n = nbase + nd;
    const int e0 = offs[n], e1 = offs[n + 1];
    const unsigned short* hb = H + (long)bt * NN * 384 + sub * 24;
    float acc24[24];
#pragma unroll
    for (int i = 0; i < 24; i++) acc24[i] = 0.f;

#define ACC8(base, u)                                                   \
    { acc24[base+0] += bflo(u.x); acc24[base+1] += bfhi(u.x);           \
      acc24[base+2] += bflo(u.y); acc24[base+3] += bfhi(u.y);           \
      acc24[base+4] += bflo(u.z); acc24[base+5] += bfhi(u.z);           \
      acc24[base+6] += bflo(u.w); acc24[base+7] += bfhi(u.w); }
#define LDPAIR(B0,B1,B2,B3,B4,B5, jj)                                   \
    { int s0 = csr[jj], s1 = csr[(jj) + 1];                             \
      const unsigned short* p0 = hb + (long)s0 * 384;                   \
      const unsigned short* p1 = hb + (long)s1 * 384;                   \
      B0 = *(const uint4*)(p0);  B1 = *(const uint4*)(p0 + 8);          \
      B2 = *(const uint4*)(p0 + 16);                                    \
      B3 = *(const uint4*)(p1);  B4 = *(const uint4*)(p1 + 8);          \
      B5 = *(const uint4*)(p1 + 16); }
#define ACCP(B0,B1,B2,B3,B4,B5)                                         \
    { ACC8(0,B0) ACC8(8,B1) ACC8(16,B2) ACC8(0,B3) ACC8(8,B4) ACC8(16,B5) }

    const int npair = (e1 - e0) >> 1;
    int j = e0;
    if (npair > 0) {
      uint4 a0, a1, a2, a3, a4, a5;
      uint4 b0, b1, b2, b3, b4, b5;
      LDPAIR(a0, a1, a2, a3, a4, a5, j);
      int g = 0;
      while (true) {
        if (g + 1 < npair) {
          LDPAIR(b0, b1, b2, b3, b4, b5, j + 2);   // in flight while acc A
          ACCP(a0, a1, a2, a3, a4, a5);
          g++; j += 2;
          if (g + 1 < npair) {
            LDPAIR(a0, a1, a2, a3, a4, a5, j + 2); // in flight while acc B
            ACCP(b0, b1, b2, b3, b4, b5);
            g++; j += 2;
          } else {
            ACCP(b0, b1, b2, b3, b4, b5);
            g++; j += 2;
            break;
          }
        } else {
          ACCP(a0, a1, a2, a3, a4, a5);
          g++; j += 2;
          break;
        }
      }
    }
    if (j < e1) {   // at most one leftover edge
      int s0 = csr[j];
      const unsigned short* p0 = hb + (long)s0 * 384;
      uint4 A0 = *(const uint4*)(p0);
      uint4 A1 = *(const uint4*)(p0 + 8);
      uint4 A2 = *(const uint4*)(p0 + 16);
      ACC8(0, A0) ACC8(8, A1) ACC8(16, A2)
    }
#undef ACCP
#undef LDPAIR
#undef ACC8
    // write agg -> xS rows (3*nd + a), packed pairs (pairs never cross a)
#pragma unroll
    for (int jj = 0; jj < 12; jj++) {
      int g = sub * 24 + 2 * jj;
      int a_ = g >> 7;
      int c = g & 127;
      *(unsigned*)&xS[(3 * nd + a_) * XSTR + c] =
          pk_bf16(acc24[2 * jj], acc24[2 * jj + 1]);
    }
  }
  __syncthreads();

  const int w = tid >> 6;
  const int l = tid & 63;
  const int lr = l & 15;
  const int lg = l >> 4;
  const unsigned short* WQ = WF;
  const unsigned short* WK = WF + 16384;
  const unsigned short* WV = WF + 32768;
  const unsigned short* WO = WF + 49152;

  // ---- phase 1: QKV projections ----
  v4f accq[3][2], acck[3][2], accv[3][2];
#pragma unroll
  for (int mt = 0; mt < 3; mt++)
#pragma unroll
    for (int n = 0; n < 2; n++) {
      accq[mt][n] = (v4f){0.f, 0.f, 0.f, 0.f};
      acck[mt][n] = (v4f){0.f, 0.f, 0.f, 0.f};
      accv[mt][n] = (v4f){0.f, 0.f, 0.f, 0.f};
    }
#pragma unroll
  for (int kt = 0; kt < 4; kt++) {
    short8 af[3];
#pragma unroll
    for (int mt = 0; mt < 3; mt++)
      af[mt] = *(const short8*)&xS[(mt * 16 + lr) * XSTR + kt * 32 + lg * 8];
#pragma unroll
    for (int ntl = 0; ntl < 2; ntl++) {
      long tf = (long)(kt * 8 + 2 * w + ntl) * 512 + l * 8;
      short8 b0 = *(const short8*)&WQ[tf];
      short8 b1 = *(const short8*)&WK[tf];
      short8 b2 = *(const short8*)&WV[tf];
#pragma unroll
      for (int mt = 0; mt < 3; mt++) {
        accq[mt][ntl] = __builtin_amdgcn_mfma_f32_16x16x32_bf16(af[mt], b0, accq[mt][ntl], 0, 0, 0);
        acck[mt][ntl] = __builtin_amdgcn_mfma_f32_16x16x32_bf16(af[mt], b1, acck[mt][ntl], 0, 0, 0);
        accv[mt][ntl] = __builtin_amdgcn_mfma_f32_16x16x32_bf16(af[mt], b2, accv[mt][ntl], 0, 0, 0);
      }
    }
  }
  __syncthreads();   // all waves' xS (agg) MFMA reads complete

  // residual pre-read (per-wave own head cols of xS), THEN write Q over them
  float resv[3][2][4];
#pragma unroll
  for (int mt = 0; mt < 3; mt++)
#pragma unroll
    for (int ntl = 0; ntl < 2; ntl++)
#pragma unroll
      for (int i = 0; i < 4; i++)
        resv[mt][ntl][i] =
            bf2f(xS[(mt * 16 + lg * 4 + i) * XSTR + 32 * w + ntl * 16 + lr]);

  {
    const float scale = 0.17677669529663687f;  // 1/sqrt(32)
    unsigned short* kw = &kS[w * 48 * QSTR];
    unsigned short* vw = &vS[w * 48 * QSTR];
    float bqv[2] = {bq[32 * w + lr], bq[32 * w + 16 + lr]};
    float bkv[2] = {bk[32 * w + lr], bk[32 * w + 16 + lr]};
    float bvv[2] = {bv[32 * w + lr], bv[32 * w + 16 + lr]};
#pragma unroll
    for (int mt = 0; mt < 3; mt++)
#pragma unroll
      for (int ntl = 0; ntl < 2; ntl++)
#pragma unroll
        for (int i = 0; i < 4; i++) {
          int row = mt * 16 + lg * 4 + i;
          int col = ntl * 16 + lr;
          xS[row * XSTR + 32 * w + col] = f2bf((accq[mt][ntl][i] + bqv[ntl]) * scale);
          kw[row * QSTR + col] = f2bf(acck[mt][ntl][i] + bkv[ntl]);
          vw[row * QSTR + col] = f2bf(accv[mt][ntl][i] + bvv[ntl]);
        }
  }
  __syncthreads();

  // ---- phase 2: attention; lane l<48 owns (nd=l/3, aq=l%3) of head w.
  // O overwrites lane's own Q row in xS — race-free.
  if (l < 48) {
    int aq = l % 3;
    int ndr = l - aq;
    const unsigned* qr = (const unsigned*)&xS[l * XSTR + 32 * w];
    const unsigned* kr0 = (const unsigned*)&kS[(w * 48 + ndr) * QSTR];
    const unsigned* kr1 = (const unsigned*)&kS[(w * 48 + ndr + 1) * QSTR];
    const unsigned* kr2 = (const unsigned*)&kS[(w * 48 + ndr + 2) * QSTR];
    float s0 = 0.f, s1 = 0.f, s2 = 0.f;
#pragma unroll
    for (int j = 0; j < 16; j++) {
      unsigned uq = qr[j], u0 = kr0[j], u1 = kr1[j], u2 = kr2[j];
      float qa = bflo(uq), qb = bfhi(uq);
      s0 = fmaf(qa, bflo(u0), fmaf(qb, bfhi(u0), s0));
      s1 = fmaf(qa, bflo(u1), fmaf(qb, bfhi(u1), s1));
      s2 = fmaf(qa, bflo(u2), fmaf(qb, bfhi(u2), s2));
    }
    float mx = fmaxf(s0, fmaxf(s1, s2));
    float e0 = expf(s0 - mx), e1 = expf(s1 - mx), e2 = expf(s2 - mx);
    float inv = 1.0f / (e0 + e1 + e2);
    e0 *= inv; e1 *= inv; e2 *= inv;
    const unsigned* vr0 = (const unsigned*)&vS[(w * 48 + ndr) * QSTR];
    const unsigned* vr1 = (const unsigned*)&vS[(w * 48 + ndr + 1) * QSTR];
    const unsigned* vr2 = (const unsigned*)&vS[(w * 48 + ndr + 2) * QSTR];
    unsigned ov[16];
#pragma unroll
    for (int j = 0; j < 16; j++) {
      unsigned u0 = vr0[j], u1 = vr1[j], u2 = vr2[j];
      float oa = fmaf(e0, bflo(u0), fmaf(e1, bflo(u1), e2 * bflo(u2)));
      float ob = fmaf(e0, bfhi(u0), fmaf(e1, bfhi(u1), e2 * bfhi(u2)));
      ov[j] = pk_bf16(oa, ob);
    }
    uint4* orow = (uint4*)&xS[l * XSTR + 32 * w];
    orow[0] = make_uint4(ov[0], ov[1], ov[2], ov[3]);
    orow[1] = make_uint4(ov[4], ov[5], ov[6], ov[7]);
    orow[2] = make_uint4(ov[8], ov[9], ov[10], ov[11]);
    orow[3] = make_uint4(ov[12], ov[13], ov[14], ov[15]);
  }
  __syncthreads();

  // ---- phase 3: hI = agg + O @ Wo + bo ----
  v4f acco[3][2];
#pragma unroll
  for (int mt = 0; mt < 3; mt++)
#pragma unroll
    for (int n = 0; n < 2; n++) acco[mt][n] = (v4f){0.f, 0.f, 0.f, 0.f};
#pragma unroll
  for (int kt = 0; kt < 4; kt++) {
    short8 af[3];
#pragma unroll
    for (int mt = 0; mt < 3; mt++)
      af[mt] = *(const short8*)&xS[(mt * 16 + lr) * XSTR + kt * 32 + lg * 8];
#pragma unroll
    for (int ntl = 0; ntl < 2; ntl++) {
      long tf = (long)(kt * 8 + 2 * w + ntl) * 512 + l * 8;
      short8 b = *(const short8*)&WO[tf];
#pragma unroll
      for (int mt = 0; mt < 3; mt++)
        acco[mt][ntl] = __builtin_amdgcn_mfma_f32_16x16x32_bf16(af[mt], b, acco[mt][ntl], 0, 0, 0);
    }
  }
  __syncthreads();   // all O reads of xS done

  // write hI into xS, a-major rows: row' = a*16 + nd  (orig row = 3*nd + a)
  {
    float bov[2] = {bo[32 * w + lr], bo[32 * w + 16 + lr]};
#pragma unroll
    for (int mt = 0; mt < 3; mt++)
#pragma unroll
      for (int ntl = 0; ntl < 2; ntl++)
#pragma unroll
        for (int i = 0; i < 4; i++) {
          int row = mt * 16 + lg * 4 + i;
          int nd = row / 3, a_ = row - nd * 3;
          int gcol = 32 * w + ntl * 16 + lr;
          xS[(a_ * 16 + nd) * XSTR + gcol] =
              f2bf(acco[mt][ntl][i] + bov[ntl] + resv[mt][ntl][i]);
        }
  }
  __syncthreads();

  // ---- phase 4: m = relu(hI @ mu_W1[a] + mb1[a]); tile mt == a ----
  v4f accm[3][2];
#pragma unroll
  for (int mt = 0; mt < 3; mt++)
#pragma unroll
    for (int n = 0; n < 2; n++) accm[mt][n] = (v4f){0.f, 0.f, 0.f, 0.f};
#pragma unroll
  for (int kt = 0; kt < 4; kt++) {
#pragma unroll
    for (int mt = 0; mt < 3; mt++) {
      short8 af = *(const short8*)&xS[(mt * 16 + lr) * XSTR + kt * 32 + lg * 8];
#pragma unroll
      for (int ntl = 0; ntl < 2; ntl++) {
        short8 b = *(const short8*)(WM1 + (long)mt * 16384 +
                                    (long)(kt * 8 + 2 * w + ntl) * 512 + l * 8);
        accm[mt][ntl] = __builtin_amdgcn_mfma_f32_16x16x32_bf16(af, b, accm[mt][ntl], 0, 0, 0);
      }
    }
  }
  __syncthreads();   // all hI reads done

  // write m into xS (already a-major: tile mt rows = a*16 + nd)
#pragma unroll
  for (int mt = 0; mt < 3; mt++)
#pragma unroll
    for (int ntl = 0; ntl < 2; ntl++) {
      int col = 32 * w + ntl * 16 + lr;
      float bias = mb1[mt * 128 + col];
#pragma unroll
      for (int i = 0; i < 4; i++) {
        int rowp = mt * 16 + lg * 4 + i;
        xS[rowp * XSTR + col] = f2bf(fmaxf(accm[mt][ntl][i] + bias, 0.0f));
      }
    }
  __syncthreads();

  // ---- phase 5: mu = m @ mu_W2[a] + mb2[a]; wave w handles a = w (w<3) ----
  if (w < 3) {
    v4f accu = (v4f){0.f, 0.f, 0.f, 0.f};
#pragma unroll
    for (int kt = 0; kt < 4; kt++) {
      short8 af = *(const short8*)&xS[(w * 16 + lr) * XSTR + kt * 32 + lg * 8];
      short8 b = *(const short8*)(WM2 + w * 2048 + kt * 512 + l * 8);
      accu = __builtin_amdgcn_mfma_f32_16x16x32_bf16(af, b, accu, 0, 0, 0);
    }
    float bias = mb2[w * 16 + lr];
#pragma unroll
    for (int i = 0; i < 4; i++) {
      int nd = lg * 4 + i;
      float mu = accu[i] + bias;
      unsigned gidx = (unsigned)((node0 + nd) * 48 + w * 16 + lr);
      unsigned bits = jax_random_bits32(gidx);
      float noise = jax_normal_from_bits(bits);
      float sample = mu + noise;
      float lp = -0.9189385332046727f - 0.5f * noise * noise;
      lp += __shfl_xor(lp, 1, 64);
      lp += __shfl_xor(lp, 2, 64);
      lp += __shfl_xor(lp, 4, 64);
      lp += __shfl_xor(lp, 8, 64);
      if (lr == 0) lpS[w * 16 + nd] = lp;
      float res;
      if (w == 0) {
        float th = tanhf(sample);
        float mx = th;
        mx = fmaxf(mx, __shfl_xor(mx, 1, 64));
        mx = fmaxf(mx, __shfl_xor(mx, 2, 64));
        mx = fmaxf(mx, __shfl_xor(mx, 4, 64));
        mx = fmaxf(mx, __shfl_xor(mx, 8, 64));
        float ex = expf(th - mx);
        float ss = ex;
        ss += __shfl_xor(ss, 1, 64);
        ss += __shfl_xor(ss, 2, 64);
        ss += __shfl_xor(ss, 4, 64);
        ss += __shfl_xor(ss, 8, 64);
        res = ex / ss;
      } else if (w == 1) {
        res = 1.0f / (1.0f + expf(-sample));
      } else {
        res = tanhf(sample);
      }
      out0[gidx] = res;
    }
  }
  __syncthreads();
  if (tid < 16)
    out1[node0 + tid] = lpS[tid] + lpS[16 + tid] + lpS[32 + tid];
}

// ---------------------------------------------------------------------------
extern "C" void kernel_launch(void* const* d_in, const int* in_sizes, int n_in,
                              void* d_out, int out_size, void* d_ws, size_t ws_size,
                              hipStream_t stream) {
  const float* x = (const float*)d_in[0];
  const int* ei = (const int*)d_in[1];
  const float* W1 = (const float*)d_in[2];
  const float* b1 = (const float*)d_in[3];
  const float* W2 = (const float*)d_in[4];
  const float* b2 = (const float*)d_in[5];
  const float* Wq = (const float*)d_in[6];
  const float* bq = (const float*)d_in[7];
  const float* Wk = (const float*)d_in[8];
  const float* bk = (const float*)d_in[9];
  const float* Wv = (const float*)d_in[10];
  const float* bv = (const float*)d_in[11];
  const float* Wo = (const float*)d_in[12];
  const float* bo = (const float*)d_in[13];
  const float* mW1 = (const float*)d_in[14];
  const float* mb1 = (const float*)d_in[15];
  const float* mW2 = (const float*)d_in[16];
  const float* mb2 = (const float*)d_in[17];
  (void)in_sizes; (void)n_in; (void)out_size; (void)ws_size;

  unsigned short* HB = (unsigned short*)d_ws;      // 12,582,912 (h bf16)
  int* deg = (int*)(HB + 12582912);                // 16384
  int* offs = deg + NN;                            // 16385
  int* cur = offs + (NN + 1);                      // 16384
  int* csr = cur + NN;                             // 262144
  unsigned short* wfrag = (unsigned short*)(((uintptr_t)(csr + EE) + 15) & ~(uintptr_t)15);
  unsigned short* w2frag = wfrag + 13 * 16384;     // 3*2048

  const int* dst = ei;
  const int* srcv = ei + EE;

  float* out0 = (float*)d_out;
  float* out1 = out0 + TOT_NOISE;

  hipMemsetAsync(deg, 0, NN * sizeof(int), stream);
  edge_count<<<EE / 256, 256, 0, stream>>>(dst, deg);
  scan_k<<<1, 1024, 0, stream>>>(deg, offs, cur);
  edge_fill<<<EE / 256, 256, 0, stream>>>(dst, srcv, cur, csr);
  prep_wfrag<<<dim3(64, 14), 256, 0, stream>>>(W1, W2, mW1, Wq, Wk, Wv, Wo, mW2, wfrag);

  // h = relu(x@W1+b1)@W2 + b2  (fused 2-layer MLP)
  mlp_fused<<<dim3(BNODES / 128, 3), 256, 0, stream>>>(x, wfrag, b1, wfrag + 3 * 16384, b2, HB);
  // gather + attention + hI + mu-MLP + noise/logp (mega-fused)
  attn_mega<<<BNODES / 16, 256, 0, stream>>>(HB, offs, csr,
                                             wfrag + 9 * 16384, bq, bk, bv, bo,
                                             wfrag + 6 * 16384, mb1, w2frag, mb2,
                                             out0, out1);
}